// Round 9
// baseline (139.962 us; speedup 1.0000x reference)
//
#include <hip/hip_runtime.h>

// Problem constants (from reference)
#define T_TREES 200
#define BATCH   2048
#define D_FEAT  512
#define N_NODE  64
#define LR      0.01f

typedef __attribute__((__ext_vector_type__(8)))  __bf16 bf16x8;
typedef __attribute__((__ext_vector_type__(16))) float  f32x16;

__device__ __forceinline__ unsigned short f32_to_bf16(float f) {
    unsigned u = __float_as_uint(f);
    u += 0x7FFFu + ((u >> 16) & 1u);   // RNE
    return (unsigned short)(u >> 16);
}

__device__ __forceinline__ void gload_lds16(const void* g, void* l) {
    __builtin_amdgcn_global_load_lds(
        (__attribute__((address_space(1))) void*)(void*)g,
        (__attribute__((address_space(3))) void*)l,
        16, 0, 0);
}

// ---------------- fused prep kernel ----------------
// kg-major layouts so main-kernel access is contiguous:
// x_p[mt 16][kg 64][m 128][8k] bf16 ; w_p[pair 100][kg 64][n' 128][8k] bf16 ;
// w_dt[t 200][32 node][64 n] bf16.
// XCD-affine placement (r8, banked best): writer of w_p[pair] runs on
// blockIdx%8 == pair/13 == the XCD whose main blocks read it.
// Grid 3584: [0,256) prep_x | [256,1920) prep_wt | [1920,3584) prep_wd.
__global__ __launch_bounds__(256) void prep_all(
    const float* __restrict__ x, const float* __restrict__ w_t,
    const float* __restrict__ w_d,
    unsigned short* __restrict__ x_p, unsigned short* __restrict__ w_p,
    unsigned short* __restrict__ w_dt) {
    __shared__ float tile[64 * 65];
    int b = blockIdx.x;
    if (b < 256) {
        // ---- x [2048][512] f32 -> x_p ----  (read by all XCDs; no affinity)
        int mb = b >> 3, slab = b & 7;
        const float* src = x + (mb * 64) * D_FEAT + slab * 64;
        #pragma unroll
        for (int p = 0; p < 16; ++p) {
            int idx = p * 256 + threadIdx.x;
            int r = idx >> 6, c = idx & 63;
            tile[r * 65 + c] = src[r * D_FEAT + c];
        }
        __syncthreads();
        int mt = mb >> 1, mq = mb & 1;
        unsigned short* dst = x_p + mt * 65536 + slab * 8192 + mq * 512;
        #pragma unroll
        for (int p = 0; p < 2; ++p) {
            int sid = p * 256 + threadIdx.x;   // 0..511
            int kgl = sid >> 6;                 // 0..7
            int r   = sid & 63;
            const float* sr = &tile[r * 65 + kgl * 8];
            bf16x8 o;
            #pragma unroll
            for (int j = 0; j < 8; ++j) o[j] = (__bf16)sr[j];
            *(bf16x8*)(dst + kgl * 1024 + r * 8) = o;
        }
    } else if (b < 1920) {
        // ---- w_t -> w_p, XCD-affine: xcd g owns pairs [13g, 13g+13) ----
        int g  = b & 7;
        int j  = (b - 256) >> 3;     // 0..207
        int pj = j >> 4;             // 0..12
        int r8 = j & 15;
        int tq = r8 >> 3, slab = r8 & 7;
        int pair = g * 13 + pj;
        if (pair >= 100) return;
        int t = pair * 2 + tq;
        const float* src = w_t + t * (D_FEAT * N_NODE) + slab * 64 * N_NODE;
        #pragma unroll
        for (int p = 0; p < 16; ++p) {
            int idx = p * 256 + threadIdx.x;
            int d = idx >> 6, n = idx & 63;
            tile[d * 65 + n] = src[d * N_NODE + n];
        }
        __syncthreads();
        unsigned short* dst = w_p + pair * 65536 + slab * 8192 + tq * 512;
        #pragma unroll
        for (int p = 0; p < 2; ++p) {
            int sid = p * 256 + threadIdx.x;   // 0..511
            int kgl = sid >> 6;                 // 0..7
            int n   = sid & 63;
            bf16x8 o;
            #pragma unroll
            for (int j2 = 0; j2 < 8; ++j2) o[j2] = (__bf16)tile[(kgl * 8 + j2) * 65 + n];
            *(bf16x8*)(dst + kgl * 1024 + n * 8) = o;
        }
    } else {
        // ---- w_d -> w_dt, XCD-affine: xcd g owns trees [26g, 26g+26) ----
        int g = b & 7;               // 1920%8==0
        int j = (b - 1920) >> 3;     // 0..207
        int t = g * 26 + (j >> 3);
        if (t >= 200) return;
        int sub = j & 7;
        int e = t * 2048 + sub * 256 + threadIdx.x;
        int n = e & 63;
        int l = (e >> 6) & 31;
        float v = (l < 15) ? w_d[(t * 64 + n) * 15 + l] : 0.f;
        w_dt[e] = f32_to_bf16(v);
    }
}

// ---------------- main fused kernel ----------------
// BARRIER-FREE WAVE-PRIVATE (r8 post-mortem: six barrier-structured
// schedules pinned at ~45 µs / MfmaUtil 25%; the invariant was the
// intra-block barrier convoy, so remove barriers entirely).
// Block = 1 wave (64 thr). Wave owns (pair = 2 trees) x (64 batch rows).
// A register-direct ping-pong from x_p (r4 path); B chunks (8 KB,
// [4 kg][128 col][8k]) staged into WAVE-PRIVATE LDS dbuf via
// global_load_lds -> zero s_barrier/__syncthreads in the whole kernel.
// Ordering = counted vmcnt only: iter c issues B(c+1):8 + A(c+1):4, then
// s_waitcnt vmcnt(12) lands everything older (B(c),A(c)) while the 12 new
// stay in flight. 16 MFMA/chunk (acc[2][4], 128 AGPR). LDS 17408 B ->
// 9 blocks/CU (~156 KB), regs ~210 -> 9 free-running waves/CU absorb each
// other's stalls. Epilogue wave-private: H[64][136] bf16 overlay, GEMM2
// (16 MFMA), P[2][64][17] f32 overlay, routing 2 jobs/lane; the only sync
// is wave-local s_waitcnt lgkmcnt(0) at the two LDS reuse points.
__global__ __launch_bounds__(64, 2) void gbdt_main(
    const unsigned short* __restrict__ x_p,    // [16][64][128][8] bf16
    const unsigned short* __restrict__ w_p,    // [100][64][128][8] bf16
    const unsigned short* __restrict__ w_dt,   // [200][32][64] bf16
    const float* __restrict__ b_t,             // [200][64]
    const float* __restrict__ b_d,             // [200][15]
    const float* __restrict__ w_l,             // [200][16]
    const float* __restrict__ b_l,             // [200]
    float* __restrict__ f_ws)                  // [2048][200]  (b-major)
{
    // LDS (per 64-thread block = per wave): B dbuf [0,16384).
    // Overlays: H [0,17408) = [64 m][136 col] bf16 (272 B stride, 16B-aligned
    // frag reads, ~4-way bank alias on 16 GEMM2 reads = negligible);
    // P [0,8704) = [2 tree][64 m][17] f32.
    __shared__ alignas(16) char smem[17408];
    unsigned short* Hs = (unsigned short*)smem;
    __bf16*         Hb = (__bf16*)smem;
    float*          Pf = (float*)smem;

    const int tid    = threadIdx.x;      // 0..63
    const int lane31 = tid & 31;
    const int kh     = tid >> 5;

    const int b    = blockIdx.x;
    const int xcd  = b & 7;
    const int s    = b >> 3;             // 0..415
    const int jobm = s & 31;             // 64-row tile (0..31)
    const int pj   = s >> 5;             // 0..12
    const int pair = xcd * 13 + pj;
    if (pair >= 100) return;
    const int t0   = pair * 2;
    const int mt   = jobm >> 1;          // x_p 128-slab
    const int half = jobm & 1;           // which 64-row half of the slab

    // A frag base (elems): frag(c,s2,mb) at pA + c*4096 + s2*2048 + mb*256
    const unsigned short* pA =
        x_p + mt * 65536 + kh * 1024 + half * 512 + lane31 * 8;
    // B staging source (bytes): chunk stride 8192; wave covers 8 KB as
    // 8 x (uniform base + lane*16) runs of 1 KB.
    const char* gb = (const char*)(w_p + pair * 65536) + tid * 16;

    f32x16 acc[2][4];
    #pragma unroll
    for (int mb = 0; mb < 2; ++mb)
        #pragma unroll
        for (int nb = 0; nb < 4; ++nb)
            acc[mb][nb] = (f32x16)(0.f);

#define LOAD_A(cn, areg) do {                                      \
        _Pragma("unroll")                                          \
        for (int s2 = 0; s2 < 2; ++s2)                             \
            _Pragma("unroll")                                      \
            for (int mb = 0; mb < 2; ++mb)                         \
                (areg)[s2 * 2 + mb] =                              \
                    *(const bf16x8*)(pA + (cn) * 4096 + s2 * 2048 + mb * 256); \
    } while (0)

#define STAGE_B(cn, base) do {                                     \
        _Pragma("unroll")                                          \
        for (int k = 0; k < 8; ++k)                                \
            gload_lds16(gb + (cn) * 8192 + k * 1024,               \
                        (base) + tid * 16 + k * 1024);             \
    } while (0)

    bf16x8 aC[4], aN[4];
    STAGE_B(0, smem);
    LOAD_A(0, aC);

    // ---- K loop: 16 chunks of 32; wave-private, counted vmcnt, NO barriers.
    // Top of iter c after issuing (c+1)'s 12 loads: outstanding =
    // [B(c):8?, A(c):4?, B(c+1):8, A(c+1):4] -> vmcnt(12) lands all of
    // iter c's data, keeps iter c+1's 12 in flight.
    #pragma unroll
    for (int c = 0; c < 16; ++c) {
        if (c < 15) {
            STAGE_B(c + 1, smem + ((c + 1) & 1) * 8192);
            LOAD_A(c + 1, aN);
            asm volatile("s_waitcnt vmcnt(12)" ::: "memory");
        } else {
            asm volatile("s_waitcnt vmcnt(0)" ::: "memory");
        }
        const char* buf = smem + (c & 1) * 8192;
        __builtin_amdgcn_s_setprio(1);
        #pragma unroll
        for (int s2 = 0; s2 < 2; ++s2) {
            const int kgl = 2 * s2 + kh;
            bf16x8 bv[4];
            #pragma unroll
            for (int nb = 0; nb < 4; ++nb)
                bv[nb] = *(const bf16x8*)(buf + (kgl * 128 + nb * 32 + lane31) * 16);
            #pragma unroll
            for (int mb = 0; mb < 2; ++mb)
                #pragma unroll
                for (int nb = 0; nb < 4; ++nb)
                    acc[mb][nb] = __builtin_amdgcn_mfma_f32_32x32x16_bf16(
                        aC[s2 * 2 + mb], bv[nb], acc[mb][nb], 0, 0, 0);
        }
        __builtin_amdgcn_s_setprio(0);
        #pragma unroll
        for (int i = 0; i < 4; ++i) aC[i] = aN[i];
    }

    // ---- epilogue: h = relu(acc + b_t) -> H LDS [64][136] (wave-private).
    // C/D layout (32x32): col = lane&31, row = (r&3) + 8*(r>>2) + 4*(lane>>5)
    #pragma unroll
    for (int nb = 0; nb < 4; ++nb) {
        // global col = nb*32 + lane31: tree = nb>>1, node = (nb&1)*32+lane31
        float btv = b_t[(t0 + (nb >> 1)) * 64 + (nb & 1) * 32 + lane31];
        #pragma unroll
        for (int mb = 0; mb < 2; ++mb)
            #pragma unroll
            for (int r = 0; r < 16; ++r) {
                int m = mb * 32 + (r & 3) + 8 * (r >> 2) + 4 * kh;
                float hv = fmaxf(acc[mb][nb][r] + btv, 0.f);
                Hb[m * 136 + nb * 32 + lane31] = (__bf16)hv;
            }
    }
    // wave-local: all 64 lanes' H writes visible before GEMM2 reads
    asm volatile("s_waitcnt lgkmcnt(0)" ::: "memory");

    // ---- GEMM2: per tree j: logit[64 m x 16 l], K=64 ----
    f32x16 acc2[2][2];
    #pragma unroll
    for (int j = 0; j < 2; ++j)
        #pragma unroll
        for (int i = 0; i < 2; ++i)
            acc2[j][i] = (f32x16)(0.f);
    #pragma unroll
    for (int j = 0; j < 2; ++j) {
        const unsigned short* pW = w_dt + (t0 + j) * 2048 + lane31 * 64 + kh * 8;
        #pragma unroll
        for (int s4 = 0; s4 < 4; ++s4) {
            bf16x8 bv = *(const bf16x8*)(pW + s4 * 16);
            #pragma unroll
            for (int i = 0; i < 2; ++i) {
                bf16x8 av = *(const bf16x8*)(
                    Hs + (i * 32 + lane31) * 136 + j * 64 + s4 * 16 + kh * 8);
                acc2[j][i] = __builtin_amdgcn_mfma_f32_32x32x16_bf16(
                    av, bv, acc2[j][i], 0, 0, 0);
            }
        }
    }
    // H reads retired (consumed by MFMA); order the P overlay writes
    asm volatile("s_waitcnt lgkmcnt(0)" ::: "memory");

    // ---- p = sigmoid(logit + b_d) -> P [2][64][17] f32 ----
    if (lane31 < 15) {
        #pragma unroll
        for (int j = 0; j < 2; ++j) {
            float bdv = b_d[(t0 + j) * 15 + lane31];
            #pragma unroll
            for (int i = 0; i < 2; ++i)
                #pragma unroll
                for (int r = 0; r < 16; ++r) {
                    int m = i * 32 + (r & 3) + 8 * (r >> 2) + 4 * kh;
                    float lg = acc2[j][i][r] + bdv;
                    Pf[(j * 64 + m) * 17 + lane31] = 1.f / (1.f + __expf(-lg));
                }
        }
    }
    asm volatile("s_waitcnt lgkmcnt(0)" ::: "memory");

    // ---- soft routing + leaf score: lane = row (64), 2 trees/lane ----
    #pragma unroll
    for (int jj = 0; jj < 2; ++jj) {
        int t = t0 + jj;
        float pv[15];
        #pragma unroll
        for (int i = 0; i < 15; ++i) pv[i] = Pf[(jj * 64 + tid) * 17 + i];
        float facc = 0.f;
        #pragma unroll
        for (int leaf = 0; leaf < 16; ++leaf) {
            float mu = 1.f;
            int node = 0;
            #pragma unroll
            for (int d = 0; d < 4; ++d) {
                int bit = (leaf >> (3 - d)) & 1;
                float p = pv[node];
                mu *= bit ? (1.f - p) : p;
                node = 2 * node + 1 + bit;
            }
            facc += mu * w_l[t * 16 + leaf];
        }
        f_ws[(jobm * 64 + tid) * T_TREES + t] = tanhf(facc + b_l[t]);
    }
#undef STAGE_B
#undef LOAD_A
}

// ---------------- boosting prefix-sum ----------------
// One WAVE per batch row (4 rows/block, grid 512). Lane l (l<50) owns
// trees 4l..4l+3 via one float4 load; local prefix-4 + 6-step shuffle
// inclusive scan of lane sums. No LDS, no __syncthreads.
__global__ __launch_bounds__(256) void scan_k(const float* __restrict__ f_ws,
                                              const float* __restrict__ f0p,
                                              float* __restrict__ out) {
    int lane = threadIdx.x & 63, wid = threadIdx.x >> 6;
    int b = blockIdx.x * 4 + wid;
    float f0 = f0p[0];
    float4 v;
    if (lane < 50) v = *(const float4*)(f_ws + b * T_TREES + lane * 4);
    else           v = make_float4(0.f, 0.f, 0.f, 0.f);
    float p0 = v.x;
    float p1 = p0 + v.y;
    float p2 = p1 + v.z;
    float p3 = p2 + v.w;
    float s = p3;
    #pragma unroll
    for (int off = 1; off < 64; off <<= 1) {
        float y = __shfl_up(s, off, 64);
        if (lane >= off) s += y;
    }
    float excl = s - p3;                 // exclusive prefix of lane sums
    if (lane < 50) {
        float* o = out + b * (T_TREES + 1) + 1 + lane * 4;
        o[0] = f0 + LR * (excl + p0);
        o[1] = f0 + LR * (excl + p1);
        o[2] = f0 + LR * (excl + p2);
        o[3] = f0 + LR * (excl + p3);
    }
    if (lane == 0) out[b * (T_TREES + 1)] = f0;
}

extern "C" void kernel_launch(void* const* d_in, const int* in_sizes, int n_in,
                              void* d_out, int out_size, void* d_ws, size_t ws_size,
                              hipStream_t stream) {
    const float* x   = (const float*)d_in[0];
    const float* w_t = (const float*)d_in[2];
    const float* b_t = (const float*)d_in[3];
    const float* w_d = (const float*)d_in[4];
    const float* b_d = (const float*)d_in[5];
    const float* w_l = (const float*)d_in[6];
    const float* b_l = (const float*)d_in[7];
    const float* f_0 = (const float*)d_in[8];
    float* out = (float*)d_out;

    char* ws = (char*)d_ws;
    unsigned short* x_p  = (unsigned short*)(ws);               // 2,097,152 B
    unsigned short* w_p  = (unsigned short*)(ws + 2097152);     // 13,107,200 B
    unsigned short* w_dt = (unsigned short*)(ws + 15204352);    //   819,200 B
    float*          f_ws = (float*)(ws + 16023552);             // 1,638,400 B

    prep_all<<<3584, 256, 0, stream>>>(x, w_t, w_d, x_p, w_p, w_dt);
    gbdt_main<<<3328, 64, 0, stream>>>(x_p, w_p, w_dt, b_t, b_d, w_l, b_l, f_ws);
    scan_k<<<512, 256, 0, stream>>>(f_ws, f_0, out);
}